// Round 5
// baseline (1232.377 us; speedup 1.0000x reference)
//
#include <hip/hip_runtime.h>
#include <hip/hip_bf16.h>

#define A_N 152
#define V_N 26
#define M_N 3952          // A_N*V_N, = 247*16 exactly
#define M_PAD 3968        // 62*64
#define CIN 512
#define FDIM 256
#define HW_SZ 16384
#define P_TOT 131072.0f   // 8*16384
#define TEMP_INV 14.285714285714286f
#define NGRP 2048         // 8 images * 256 groups of 64 px
#define LCAP 64           // max samples per pixel-group

typedef __attribute__((ext_vector_type(8))) short bf16x8;
typedef __attribute__((ext_vector_type(4))) float f32x4;
typedef __attribute__((ext_vector_type(4))) float f4raw;

static __device__ __forceinline__ short f2bf(float x){
  union { float f; unsigned u; } v; v.f = x;
  unsigned r = (v.u + 0x7FFFu + ((v.u >> 16) & 1u)) >> 16;
  return (short)r;
}

// LDS column swizzle (units: shorts). ((row&7)^((row>>3)&7)): on MFMA reads
// (rows pi*16+l, l=0..15) it gives the same 2-lanes-per-16B-slot profile as the
// old (row&7) swizzle; on the NEW coalesced-staging writes (rows 4k+j, k=0..15)
// it spreads 16 lanes over 8 slots (old swizzle collapsed them to 2 -> 8-way).
static __device__ __forceinline__ int swz(int row){
  return ((row & 7) ^ ((row >> 3) & 7)) << 3;
}

// Load an MFMA 16x16x32 A/B fragment from a row-major [rows][ld] bf16 matrix.
static __device__ __forceinline__ bf16x8 ldfrag(const short* __restrict__ base, int ld,
                                                int row, int k, int lane){
  return *(const bf16x8*)(base + (size_t)(row + (lane & 15)) * ld + k + ((lane >> 4) << 3));
}

// ---------------------------------------------------------------- weights cast (all 4 at once)
__global__ void castw_kernel(const float* __restrict__ a0, short* __restrict__ o0,
                             const float* __restrict__ a1, short* __restrict__ o1,
                             const float* __restrict__ a2, short* __restrict__ o2,
                             const float* __restrict__ a3, short* __restrict__ o3){
  const float* a; short* o; int n;
  switch (blockIdx.y){
    case 0: a = a0; o = o0; n = CIN*CIN; break;
    case 1: a = a1; o = o1; n = CIN*CIN; break;
    case 2: a = a2; o = o2; n = FDIM*CIN; break;
    default: a = a3; o = o3; n = FDIM*CIN; break;
  }
  int i = blockIdx.x * 256 + threadIdx.x;
  if (i < n) o[i] = f2bf(a[i]);
}

// ---------------------------------------------------------------- sample -> pixel-group lists
// Entry packs (px<<16)|m so the stats gather needs no dependent si load.
__global__ __launch_bounds__(64) void build_lists_kernel(
    const int* __restrict__ sb, const int* __restrict__ si,
    int* __restrict__ counts, int* __restrict__ lists){
  int m = blockIdx.x * 64 + threadIdx.x;
  if (m >= M_N) return;
  int a = m % A_N, v = m / A_N;
  int pix = si[a * V_N + v];
  int g = sb[a] * 256 + (pix >> 6);
  int slot = atomicAdd(&counts[g], 1);
  if (slot < LCAP) lists[g * LCAP + slot] = m | ((pix & 63) << 16);
}

// ---------------------------------------------------------------- BN statistics (+ fused gather)
// sums[d] = sum_p h, sums[512+d] = sum_p h^2, h = W1 . x (b1 cancels in BN).
// Structure = round-0 (best measured 405us): grid (512,2), 4 tiles/block, 64KB LDS.
// R5 single change: WAVE-COALESCED staging. Old pattern (c=tid) made every wave
// load instr touch 64 lines 64KB apart (zero intra-wave coalescing) -> 2.5-2.7TB/s
// schedule-invariant across R0/R2/R3. New pattern: wave w owns channels w*64..+63;
// per instr, 4 channel-rows x 16 lanes x 16B contiguous = 4x 256B segments.
// R4 lesson: nt-loads refuted W1-thrash theory (L3 was absorbing x; nt broke it).
__global__ __launch_bounds__(512) void stats_kernel(
    const float* __restrict__ xS, const float* __restrict__ xT,
    const short* __restrict__ w1S, const short* __restrict__ w1T,
    float* __restrict__ stats,
    const int* __restrict__ counts, const int* __restrict__ lists,
    short* __restrict__ xsS, short* __restrict__ xsT){
  __shared__ short lds[64 * 512];        // 64 px x 512 c, c XOR-swizzled by swz(px)
  const int t = blockIdx.y;
  const float* __restrict__ x = t ? xT : xS;
  const short* __restrict__ w1 = t ? w1T : w1S;
  float* sums = stats + t * 1024;
  short* __restrict__ xs = t ? xsT : xsS;

  const int tid  = threadIdx.x;
  const int lane = tid & 63;
  const int wave = tid >> 6;
  const int d0   = wave * 64;

  float rs[4] = {0.f,0.f,0.f,0.f};
  float rq[4] = {0.f,0.f,0.f,0.f};

  for (int it = 0; it < 4; ++it){
    const int g   = blockIdx.x + it * 512;   // 0..2047 pixel-groups of 64
    const int n   = g >> 8;
    const int hw0 = (g & 255) << 6;

    int cnt = counts[g];                 // hoisted: latency hides under staging
    if (cnt > LCAP) cnt = LCAP;

    // ---- coalesced staging: wave w stages channels w*64..w*64+63.
    // instr q: channels cBase+q*4+(lane>>4), pixel quad (lane&15)*4 (16B contig).
    {
      const int cBase = wave * 64;
      const int pq = (lane & 15) << 2;   // pixel quad base 0,4,..,60
      const float* wsrc = x + ((size_t)(n * CIN + cBase)) * HW_SZ + hw0 + pq;
      #pragma unroll
      for (int q = 0; q < 16; ++q){
        int cOff = q * 4 + (lane >> 4);
        f4raw v = *(const f4raw*)(wsrc + (size_t)cOff * HW_SZ);
        int c = cBase + cOff;
        lds[(pq+0)*512 + (c ^ swz(pq+0))] = f2bf(v.x);
        lds[(pq+1)*512 + (c ^ swz(pq+1))] = f2bf(v.y);
        lds[(pq+2)*512 + (c ^ swz(pq+2))] = f2bf(v.z);
        lds[(pq+3)*512 + (c ^ swz(pq+3))] = f2bf(v.w);
      }
    }
    __syncthreads();

    // fused gather: copy sampled pixel columns (bf16) out of LDS (px packed in list)
    for (int s = 0; s < cnt; ++s){
      int e = lists[g * LCAP + s];
      int m = e & 0xFFFF, px = e >> 16;
      xs[(size_t)m * CIN + tid] = lds[px * 512 + (tid ^ swz(px))];
    }

    f32x4 acc[4][4] = {};                  // [px-tile][d-tile]
    for (int kk = 0; kk < CIN; kk += 32){
      bf16x8 bfr[4];
      #pragma unroll
      for (int di = 0; di < 4; ++di) bfr[di] = ldfrag(w1, CIN, d0 + di*16, kk, lane);
      #pragma unroll
      for (int pi = 0; pi < 4; ++pi){
        int px = pi*16 + (lane & 15);
        int c  = (kk + ((lane >> 4) << 3)) ^ swz(px);
        bf16x8 af = *(const bf16x8*)(lds + px*512 + c);
        #pragma unroll
        for (int di = 0; di < 4; ++di)
          acc[pi][di] = __builtin_amdgcn_mfma_f32_16x16x32_bf16(af, bfr[di], acc[pi][di], 0, 0, 0);
      }
    }
    #pragma unroll
    for (int di = 0; di < 4; ++di){
      float s = 0.f, q2 = 0.f;
      #pragma unroll
      for (int pi = 0; pi < 4; ++pi)
        #pragma unroll
        for (int r = 0; r < 4; ++r){ float vv = acc[pi][di][r]; s += vv; q2 += vv*vv; }
      rs[di] += s; rq[di] += q2;
    }
    __syncthreads();
  }
  #pragma unroll
  for (int di = 0; di < 4; ++di){
    float s = rs[di], q2 = rq[di];
    s  += __shfl_xor(s, 16, 64);  s  += __shfl_xor(s, 32, 64);
    q2 += __shfl_xor(q2, 16, 64); q2 += __shfl_xor(q2, 32, 64);
    if ((lane & 48) == 0){
      int d = d0 + di*16 + lane;
      atomicAdd(&sums[d], s);
      atomicAdd(&sums[512 + d], q2);
    }
  }
}

// ---------------------------------------------------------------- conv1 + BN + ReLU at samples
__global__ __launch_bounds__(256) void conv1_kernel(
    const short* __restrict__ xsS, const short* __restrict__ xsT,
    const short* __restrict__ w1S, const short* __restrict__ w1T,
    const float* __restrict__ stats,
    const float* __restrict__ gS, const float* __restrict__ bS,
    const float* __restrict__ gT, const float* __restrict__ bT,
    short* __restrict__ hrS, short* __restrict__ hrT){
  const int t = blockIdx.z;
  const short* xs = t ? xsT : xsS;
  const short* w1 = t ? w1T : w1S;
  const float* sums  = stats + t * 1024;
  const float* gamma = t ? gT : gS;
  const float* beta  = t ? bT : bS;
  short* hr = t ? hrT : hrS;

  const int lane = threadIdx.x & 63;
  const int wave = threadIdx.x >> 6;
  const int m0 = blockIdx.x * 16;
  const int d0 = (blockIdx.y * 4 + wave) * 64;

  f32x4 acc[4] = {};
  for (int kk = 0; kk < CIN; kk += 32){
    bf16x8 a = ldfrag(xs, CIN, m0, kk, lane);
    #pragma unroll
    for (int di = 0; di < 4; ++di){
      bf16x8 b = ldfrag(w1, CIN, d0 + di*16, kk, lane);
      acc[di] = __builtin_amdgcn_mfma_f32_16x16x32_bf16(a, b, acc[di], 0, 0, 0);
    }
  }
  const float invP = 1.f / P_TOT;
  #pragma unroll
  for (int di = 0; di < 4; ++di){
    int d = d0 + di*16 + (lane & 15);
    float mu  = sums[d] * invP;
    float var = sums[512 + d] * invP - mu * mu;
    float sc  = gamma[d] * rsqrtf(var + 1e-5f);
    float sh  = beta[d] - mu * sc;
    #pragma unroll
    for (int r = 0; r < 4; ++r){
      int m = m0 + ((lane >> 4) << 2) + r;
      float v = fmaxf(acc[di][r] * sc + sh, 0.f);
      hr[(size_t)m * CIN + d] = f2bf(v);
    }
  }
}

// ---------------------------------------------------------------- conv2 + bias + L2 normalize
__global__ __launch_bounds__(256) void conv2_kernel(
    const short* __restrict__ hrS, const short* __restrict__ hrT,
    const short* __restrict__ w2S, const short* __restrict__ w2T,
    const float* __restrict__ b2S, const float* __restrict__ b2T,
    short* __restrict__ fS, short* __restrict__ fT){
  __shared__ float ssum[4][16];
  const int t = blockIdx.y;
  const short* hr = t ? hrT : hrS;
  const short* w2 = t ? w2T : w2S;
  const float* b2 = t ? b2T : b2S;
  short* f = t ? fT : fS;

  const int lane = threadIdx.x & 63;
  const int wave = threadIdx.x >> 6;
  const int m0 = blockIdx.x * 16;
  const int e0 = wave * 64;

  f32x4 acc[4] = {};
  for (int kk = 0; kk < CIN; kk += 32){
    bf16x8 a = ldfrag(hr, CIN, m0, kk, lane);
    #pragma unroll
    for (int ei = 0; ei < 4; ++ei){
      bf16x8 b = ldfrag(w2, CIN, e0 + ei*16, kk, lane);
      acc[ei] = __builtin_amdgcn_mfma_f32_16x16x32_bf16(a, b, acc[ei], 0, 0, 0);
    }
  }
  float z[4][4];
  float part[4] = {0.f,0.f,0.f,0.f};
  #pragma unroll
  for (int ei = 0; ei < 4; ++ei){
    int e = e0 + ei*16 + (lane & 15);
    float bb = b2[e];
    #pragma unroll
    for (int r = 0; r < 4; ++r){
      float v = acc[ei][r] + bb;
      z[ei][r] = v;
      part[r] += v * v;
    }
  }
  #pragma unroll
  for (int r = 0; r < 4; ++r){
    float p = part[r];
    p += __shfl_xor(p, 1, 64); p += __shfl_xor(p, 2, 64);
    p += __shfl_xor(p, 4, 64); p += __shfl_xor(p, 8, 64);
    part[r] = p;
  }
  if ((lane & 15) == 0){
    #pragma unroll
    for (int r = 0; r < 4; ++r) ssum[wave][((lane >> 4) << 2) + r] = part[r];
  }
  __syncthreads();
  #pragma unroll
  for (int r = 0; r < 4; ++r){
    int mrow = ((lane >> 4) << 2) + r;
    float tot = ssum[0][mrow] + ssum[1][mrow] + ssum[2][mrow] + ssum[3][mrow];
    float sc = 1.f / fmaxf(sqrtf(tot), 1e-12f);
    #pragma unroll
    for (int ei = 0; ei < 4; ++ei){
      int e = e0 + ei*16 + (lane & 15);
      f[(size_t)(m0 + mrow) * FDIM + e] = f2bf(z[ei][r] * sc);
    }
  }
}

// ---------------------------------------------------------------- logits = fa . fb^T / TEMP
// Also (optionally) writes LT = logits^T: logits(fT,fS) == logits(fS,fT)^T exactly,
// so the second logits dispatch is algebraically redundant. Transpose goes through
// a 17-padded LDS tile so LT rows are written as 64B-coalesced float4 chunks.
__global__ __launch_bounds__(64) void logits_kernel(
    const short* __restrict__ fa, const short* __restrict__ fb,
    float* __restrict__ L, float* __restrict__ LT){
  __shared__ float trl[64 * 17];
  const int lane = threadIdx.x;
  const int m0 = blockIdx.x * 16;
  const int n0 = blockIdx.y * 64;
  f32x4 acc[4] = {};
  for (int kk = 0; kk < FDIM; kk += 32){
    bf16x8 a = ldfrag(fa, FDIM, m0, kk, lane);
    #pragma unroll
    for (int ni = 0; ni < 4; ++ni){
      bf16x8 b = ldfrag(fb, FDIM, n0 + ni*16, kk, lane);
      acc[ni] = __builtin_amdgcn_mfma_f32_16x16x32_bf16(a, b, acc[ni], 0, 0, 0);
    }
  }
  #pragma unroll
  for (int ni = 0; ni < 4; ++ni){
    int colL = ni*16 + (lane & 15);
    #pragma unroll
    for (int r = 0; r < 4; ++r){
      int rowL = ((lane >> 4) << 2) + r;
      float val = acc[ni][r] * TEMP_INV;
      L[(size_t)(m0 + rowL) * M_PAD + (n0 + colL)] = val;
      trl[colL * 17 + rowL] = val;
    }
  }
  if (LT){
    __syncthreads();
    float* dst = LT + (size_t)(n0 + lane) * M_PAD + m0;
    #pragma unroll
    for (int jq = 0; jq < 4; ++jq){
      f32x4 tmp;
      tmp.x = trl[lane*17 + jq*4+0];
      tmp.y = trl[lane*17 + jq*4+1];
      tmp.z = trl[lane*17 + jq*4+2];
      tmp.w = trl[lane*17 + jq*4+3];
      *(f32x4*)(dst + jq*4) = tmp;
    }
  }
}

// ---------------------------------------------------------------- per-row contrastive reduction
__global__ __launch_bounds__(256) void loss_kernel(
    const float* __restrict__ L, const int* __restrict__ labels, float* __restrict__ out){
  __shared__ float row[M_N];
  __shared__ float red[4];
  const int m1 = blockIdx.x;
  const int tid = threadIdx.x;
  const int lab1 = labels[m1 % A_N];
  const float* Lr = L + (size_t)m1 * M_PAD;

  float mx = -3.4e38f;
  for (int j = tid; j < M_N; j += 256){ float v = Lr[j]; row[j] = v; mx = fmaxf(mx, v); }
  #pragma unroll
  for (int s = 1; s < 64; s <<= 1) mx = fmaxf(mx, __shfl_xor(mx, s, 64));
  if ((tid & 63) == 0) red[tid >> 6] = mx;
  __syncthreads();
  mx = fmaxf(fmaxf(red[0], red[1]), fmaxf(red[2], red[3]));
  __syncthreads();

  float negp = 0.f;
  for (int j = tid; j < M_N; j += 256){
    int labj = labels[j % A_N];
    float e = __expf(row[j] - mx);
    negp += (labj != lab1) ? e : 0.f;
  }
  #pragma unroll
  for (int s = 1; s < 64; s <<= 1) negp += __shfl_xor(negp, s, 64);
  if ((tid & 63) == 0) red[tid >> 6] = negp;
  __syncthreads();
  float neg = red[0] + red[1] + red[2] + red[3];
  __syncthreads();

  float ps = 0.f, pc = 0.f;
  for (int j = tid; j < M_N; j += 256){
    int labj = labels[j % A_N];
    if (labj == lab1 && j != m1){
      float l = row[j] - mx;
      ps += l - __logf(__expf(l) + neg);
      pc += 1.f;
    }
  }
  #pragma unroll
  for (int s = 1; s < 64; s <<= 1) ps += __shfl_xor(ps, s, 64);
  #pragma unroll
  for (int s = 1; s < 64; s <<= 1) pc += __shfl_xor(pc, s, 64);
  if ((tid & 63) == 0) red[tid >> 6] = ps;
  __syncthreads();
  ps = red[0] + red[1] + red[2] + red[3];
  __syncthreads();
  if ((tid & 63) == 0) red[tid >> 6] = pc;
  __syncthreads();
  if (tid == 0){
    pc = red[0] + red[1] + red[2] + red[3];
    float mlpp = ps / (pc + 1e-6f);
    atomicAdd(out, -0.5f / (float)M_N * mlpp);
  }
}

// ---------------------------------------------------------------- host launch
extern "C" void kernel_launch(void* const* d_in, const int* in_sizes, int n_in,
                              void* d_out, int out_size, void* d_ws, size_t ws_size,
                              hipStream_t stream){
  const float* xS     = (const float*)d_in[0];
  const float* xT     = (const float*)d_in[1];
  const int*   sb     = (const int*)d_in[2];
  const int*   si     = (const int*)d_in[3];
  const int*   labels = (const int*)d_in[4];
  const float* sW1    = (const float*)d_in[5];
  const float* sGamma = (const float*)d_in[7];
  const float* sBeta  = (const float*)d_in[8];
  const float* sW2    = (const float*)d_in[9];
  const float* sB2    = (const float*)d_in[10];
  const float* tW1    = (const float*)d_in[11];
  const float* tGamma = (const float*)d_in[13];
  const float* tBeta  = (const float*)d_in[14];
  const float* tW2    = (const float*)d_in[15];
  const float* tB2    = (const float*)d_in[16];
  float* out = (float*)d_out;

  char* ws = (char*)d_ws;
  size_t off = 0;
  auto alloc = [&](size_t bytes) -> void* {
    void* p = ws + off;
    off = (off + bytes + 255) & ~(size_t)255;
    return p;
  };
  short* w1bS = (short*)alloc((size_t)CIN * CIN * 2);
  short* w1bT = (short*)alloc((size_t)CIN * CIN * 2);
  short* w2bS = (short*)alloc((size_t)FDIM * CIN * 2);
  short* w2bT = (short*)alloc((size_t)FDIM * CIN * 2);
  float* stats = (float*)alloc(2 * 1024 * 4);
  int* counts = (int*)alloc(NGRP * 4);
  int* lists  = (int*)alloc((size_t)NGRP * LCAP * 4);
  short* xsS = (short*)alloc((size_t)M_N * CIN * 2);
  short* xsT = (short*)alloc((size_t)M_N * CIN * 2);
  short* hrS = (short*)alloc((size_t)M_N * CIN * 2);
  short* hrT = (short*)alloc((size_t)M_N * CIN * 2);
  short* fS  = (short*)alloc((size_t)M_PAD * FDIM * 2);
  short* fT  = (short*)alloc((size_t)M_PAD * FDIM * 2);
  float* L   = (float*)alloc((size_t)M_N * M_PAD * 4);
  float* LT  = (float*)alloc((size_t)M_PAD * M_PAD * 4);
  const bool haveLT = (off <= ws_size);   // fall back to two logits passes if tight

  hipMemsetAsync(d_out, 0, sizeof(float), stream);
  hipMemsetAsync(stats, 0, 2 * 1024 * 4, stream);
  hipMemsetAsync(counts, 0, NGRP * 4, stream);
  // zero padded f rows so logits tiles touching them stay finite
  hipMemsetAsync(fS + (size_t)M_N * FDIM, 0, (size_t)(M_PAD - M_N) * FDIM * 2, stream);
  hipMemsetAsync(fT + (size_t)M_N * FDIM, 0, (size_t)(M_PAD - M_N) * FDIM * 2, stream);

  castw_kernel<<<dim3((CIN*CIN + 255) / 256, 4), 256, 0, stream>>>(
      sW1, w1bS, tW1, w1bT, sW2, w2bS, tW2, w2bT);
  build_lists_kernel<<<dim3((M_N + 63) / 64), 64, 0, stream>>>(sb, si, counts, lists);

  stats_kernel<<<dim3(512, 2), 512, 0, stream>>>(xS, xT, w1bS, w1bT, stats,
                                                 counts, lists, xsS, xsT);
  conv1_kernel<<<dim3(247, 2, 2), 256, 0, stream>>>(xsS, xsT, w1bS, w1bT, stats,
                                                    sGamma, sBeta, tGamma, tBeta, hrS, hrT);
  conv2_kernel<<<dim3(247, 2), 256, 0, stream>>>(hrS, hrT, w2bS, w2bT, sB2, tB2, fS, fT);

  if (haveLT){
    logits_kernel<<<dim3(247, 62), 64, 0, stream>>>(fS, fT, L, LT);
    loss_kernel<<<dim3(M_N), 256, 0, stream>>>(L, labels, out);
    loss_kernel<<<dim3(M_N), 256, 0, stream>>>(LT, labels, out);
  } else {
    logits_kernel<<<dim3(247, 62), 64, 0, stream>>>(fS, fT, L, nullptr);
    loss_kernel<<<dim3(M_N), 256, 0, stream>>>(L, labels, out);
    logits_kernel<<<dim3(247, 62), 64, 0, stream>>>(fT, fS, L, nullptr);
    loss_kernel<<<dim3(M_N), 256, 0, stream>>>(L, labels, out);
  }
}

// Round 6
// 689.070 us; speedup vs baseline: 1.7885x; 1.7885x over previous
//
#include <hip/hip_runtime.h>
#include <hip/hip_bf16.h>

#define A_N 152
#define V_N 26
#define M_N 3952          // A_N*V_N, = 247*16 exactly
#define M_PAD 3968        // 62*64
#define CIN 512
#define FDIM 256
#define HW_SZ 16384
#define P_TOT 131072.0f   // 8*16384
#define TEMP_INV 14.285714285714286f
#define NGRP 2048         // 8 images * 256 groups of 64 px
#define LCAP 64           // max samples per pixel-group

typedef __attribute__((ext_vector_type(8))) short bf16x8;
typedef __attribute__((ext_vector_type(4))) float f32x4;

static __device__ __forceinline__ short f2bf(float x){
  union { float f; unsigned u; } v; v.f = x;
  unsigned r = (v.u + 0x7FFFu + ((v.u >> 16) & 1u)) >> 16;
  return (short)r;
}

// Load an MFMA 16x16x32 A/B fragment from a row-major [rows][ld] bf16 matrix.
static __device__ __forceinline__ bf16x8 ldfrag(const short* __restrict__ base, int ld,
                                                int row, int k, int lane){
  return *(const bf16x8*)(base + (size_t)(row + (lane & 15)) * ld + k + ((lane >> 4) << 3));
}

// convert+store 4 px of channel tid into the XOR-swizzled [px][c] LDS tile.
// float4 BY VALUE (R1 lesson: address-taken float4 arrays go to scratch).
static __device__ __forceinline__ void cvt4(short* __restrict__ lds, float4 v,
                                            int px, int tid){
  lds[(px+0)*512 + (tid ^ (((px+0)&7)<<3))] = f2bf(v.x);
  lds[(px+1)*512 + (tid ^ (((px+1)&7)<<3))] = f2bf(v.y);
  lds[(px+2)*512 + (tid ^ (((px+2)&7)<<3))] = f2bf(v.z);
  lds[(px+3)*512 + (tid ^ (((px+3)&7)<<3))] = f2bf(v.w);
}

// ---------------------------------------------------------------- weights cast (all 4 at once)
__global__ void castw_kernel(const float* __restrict__ a0, short* __restrict__ o0,
                             const float* __restrict__ a1, short* __restrict__ o1,
                             const float* __restrict__ a2, short* __restrict__ o2,
                             const float* __restrict__ a3, short* __restrict__ o3){
  const float* a; short* o; int n;
  switch (blockIdx.y){
    case 0: a = a0; o = o0; n = CIN*CIN; break;
    case 1: a = a1; o = o1; n = CIN*CIN; break;
    case 2: a = a2; o = o2; n = FDIM*CIN; break;
    default: a = a3; o = o3; n = FDIM*CIN; break;
  }
  int i = blockIdx.x * 256 + threadIdx.x;
  if (i < n) o[i] = f2bf(a[i]);
}

// ---------------------------------------------------------------- sample -> pixel-group lists
// Entry packs (px<<16)|m so the stats gather needs no dependent si load.
__global__ __launch_bounds__(64) void build_lists_kernel(
    const int* __restrict__ sb, const int* __restrict__ si,
    int* __restrict__ counts, int* __restrict__ lists){
  int m = blockIdx.x * 64 + threadIdx.x;
  if (m >= M_N) return;
  int a = m % A_N, v = m / A_N;
  int pix = si[a * V_N + v];
  int g = sb[a] * 256 + (pix >> 6);
  int slot = atomicAdd(&counts[g], 1);
  if (slot < LCAP) lists[g * LCAP + slot] = m | ((pix & 63) << 16);
}

// ---------------------------------------------------------------- BN statistics (+ fused gather)
// sums[d] = sum_p h, sums[512+d] = sum_p h^2, h = W1 . x (b1 cancels in BN).
// Structure = round-0 (best measured 405us): grid (512,2), 4 tiles/block, 64KB LDS,
// c=tid staging in 4-load groups, (row&7)<<3 swizzle.
// R6 single change: the per-wave 64-d output is computed in TWO sequential 32-d
// passes (acc 64->32 VGPRs). Evidence: every round shows stats WRITE_SIZE ~274MB
// vs ~8MB of real writes, with a matching ~250MB FETCH excess — a symmetric
// ~512B/thread store+reload = register-spill signature at the compiler's 128-VGPR
// occupancy target (VGPR_Count=128 in ALL rounds, even when (512,2) allowed 256).
// Spill traffic+latency sits inside the MFMA loop -> schedule-invariant 405us,
// which is why R2/R3 pipelining was null. The K-loop completes within each d-pass,
// so each acc element is a full h; per-pass rs/rq folding is exact.
// R5 lesson: staging loads must issue in groups (load-use distance), never
// load->cvt interleaved per-16B (16 serial HBM latencies -> 960us).
__global__ __launch_bounds__(512) void stats_kernel(
    const float* __restrict__ xS, const float* __restrict__ xT,
    const short* __restrict__ w1S, const short* __restrict__ w1T,
    float* __restrict__ stats,
    const int* __restrict__ counts, const int* __restrict__ lists,
    short* __restrict__ xsS, short* __restrict__ xsT){
  __shared__ short lds[64 * 512];        // 64 px x 512 c, c XOR-swizzled by ((px&7)<<3)
  const int t = blockIdx.y;
  const float* __restrict__ x = t ? xT : xS;
  const short* __restrict__ w1 = t ? w1T : w1S;
  float* sums = stats + t * 1024;
  short* __restrict__ xs = t ? xsT : xsS;

  const int tid  = threadIdx.x;
  const int lane = tid & 63;
  const int wave = tid >> 6;
  const int d0   = wave * 64;

  float rs[4] = {0.f,0.f,0.f,0.f};
  float rq[4] = {0.f,0.f,0.f,0.f};

  for (int it = 0; it < 4; ++it){
    const int g   = blockIdx.x + it * 512;   // 0..2047 pixel-groups of 64
    const int n   = g >> 8;
    const int hw0 = (g & 255) << 6;
    const float* src = x + ((size_t)(n * CIN + tid)) * HW_SZ + hw0;  // c = tid

    int cnt = counts[g];                 // hoisted: latency hides under staging
    if (cnt > LCAP) cnt = LCAP;

    // stage 64 px x 512 c as bf16 in 4 chunks of 16 px (4 loads in flight/group)
    #pragma unroll
    for (int ch = 0; ch < 4; ++ch){
      float4 v0 = *(const float4*)(src + ch * 16 +  0);
      float4 v1 = *(const float4*)(src + ch * 16 +  4);
      float4 v2 = *(const float4*)(src + ch * 16 +  8);
      float4 v3 = *(const float4*)(src + ch * 16 + 12);
      cvt4(lds, v0, ch * 16 +  0, tid);
      cvt4(lds, v1, ch * 16 +  4, tid);
      cvt4(lds, v2, ch * 16 +  8, tid);
      cvt4(lds, v3, ch * 16 + 12, tid);
    }
    __syncthreads();

    // fused gather: copy sampled pixel columns (bf16) out of LDS (px packed in list)
    for (int s = 0; s < cnt; ++s){
      int e = lists[g * LCAP + s];
      int m = e & 0xFFFF, px = e >> 16;
      xs[(size_t)m * CIN + tid] = lds[px * 512 + (tid ^ ((px & 7) << 3))];
    }

    // two 32-d passes: acc is 8 f32x4 (32 VGPRs) instead of 16 (64) -> no spill
    #pragma unroll
    for (int dh = 0; dh < 2; ++dh){
      f32x4 acc[4][2] = {};                // [px-tile][d-tile within pass]
      for (int kk = 0; kk < CIN; kk += 32){
        bf16x8 b0 = ldfrag(w1, CIN, d0 + dh*32 +  0, kk, lane);
        bf16x8 b1 = ldfrag(w1, CIN, d0 + dh*32 + 16, kk, lane);
        #pragma unroll
        for (int pi = 0; pi < 4; ++pi){
          int px = pi*16 + (lane & 15);
          int c  = (kk + ((lane >> 4) << 3)) ^ ((px & 7) << 3);
          bf16x8 af = *(const bf16x8*)(lds + px*512 + c);
          acc[pi][0] = __builtin_amdgcn_mfma_f32_16x16x32_bf16(af, b0, acc[pi][0], 0, 0, 0);
          acc[pi][1] = __builtin_amdgcn_mfma_f32_16x16x32_bf16(af, b1, acc[pi][1], 0, 0, 0);
        }
      }
      #pragma unroll
      for (int dj = 0; dj < 2; ++dj){
        float s = 0.f, q2 = 0.f;
        #pragma unroll
        for (int pi = 0; pi < 4; ++pi)
          #pragma unroll
          for (int r = 0; r < 4; ++r){ float vv = acc[pi][dj][r]; s += vv; q2 += vv*vv; }
        rs[dh*2 + dj] += s; rq[dh*2 + dj] += q2;
      }
    }
    __syncthreads();
  }
  #pragma unroll
  for (int di = 0; di < 4; ++di){
    float s = rs[di], q2 = rq[di];
    s  += __shfl_xor(s, 16, 64);  s  += __shfl_xor(s, 32, 64);
    q2 += __shfl_xor(q2, 16, 64); q2 += __shfl_xor(q2, 32, 64);
    if ((lane & 48) == 0){
      int d = d0 + di*16 + lane;
      atomicAdd(&sums[d], s);
      atomicAdd(&sums[512 + d], q2);
    }
  }
}

// ---------------------------------------------------------------- conv1 + BN + ReLU at samples
__global__ __launch_bounds__(256) void conv1_kernel(
    const short* __restrict__ xsS, const short* __restrict__ xsT,
    const short* __restrict__ w1S, const short* __restrict__ w1T,
    const float* __restrict__ stats,
    const float* __restrict__ gS, const float* __restrict__ bS,
    const float* __restrict__ gT, const float* __restrict__ bT,
    short* __restrict__ hrS, short* __restrict__ hrT){
  const int t = blockIdx.z;
  const short* xs = t ? xsT : xsS;
  const short* w1 = t ? w1T : w1S;
  const float* sums  = stats + t * 1024;
  const float* gamma = t ? gT : gS;
  const float* beta  = t ? bT : bS;
  short* hr = t ? hrT : hrS;

  const int lane = threadIdx.x & 63;
  const int wave = threadIdx.x >> 6;
  const int m0 = blockIdx.x * 16;
  const int d0 = (blockIdx.y * 4 + wave) * 64;

  f32x4 acc[4] = {};
  for (int kk = 0; kk < CIN; kk += 32){
    bf16x8 a = ldfrag(xs, CIN, m0, kk, lane);
    #pragma unroll
    for (int di = 0; di < 4; ++di){
      bf16x8 b = ldfrag(w1, CIN, d0 + di*16, kk, lane);
      acc[di] = __builtin_amdgcn_mfma_f32_16x16x32_bf16(a, b, acc[di], 0, 0, 0);
    }
  }
  const float invP = 1.f / P_TOT;
  #pragma unroll
  for (int di = 0; di < 4; ++di){
    int d = d0 + di*16 + (lane & 15);
    float mu  = sums[d] * invP;
    float var = sums[512 + d] * invP - mu * mu;
    float sc  = gamma[d] * rsqrtf(var + 1e-5f);
    float sh  = beta[d] - mu * sc;
    #pragma unroll
    for (int r = 0; r < 4; ++r){
      int m = m0 + ((lane >> 4) << 2) + r;
      float v = fmaxf(acc[di][r] * sc + sh, 0.f);
      hr[(size_t)m * CIN + d] = f2bf(v);
    }
  }
}

// ---------------------------------------------------------------- conv2 + bias + L2 normalize
__global__ __launch_bounds__(256) void conv2_kernel(
    const short* __restrict__ hrS, const short* __restrict__ hrT,
    const short* __restrict__ w2S, const short* __restrict__ w2T,
    const float* __restrict__ b2S, const float* __restrict__ b2T,
    short* __restrict__ fS, short* __restrict__ fT){
  __shared__ float ssum[4][16];
  const int t = blockIdx.y;
  const short* hr = t ? hrT : hrS;
  const short* w2 = t ? w2T : w2S;
  const float* b2 = t ? b2T : b2S;
  short* f = t ? fT : fS;

  const int lane = threadIdx.x & 63;
  const int wave = threadIdx.x >> 6;
  const int m0 = blockIdx.x * 16;
  const int e0 = wave * 64;

  f32x4 acc[4] = {};
  for (int kk = 0; kk < CIN; kk += 32){
    bf16x8 a = ldfrag(hr, CIN, m0, kk, lane);
    #pragma unroll
    for (int ei = 0; ei < 4; ++ei){
      bf16x8 b = ldfrag(w2, CIN, e0 + ei*16, kk, lane);
      acc[ei] = __builtin_amdgcn_mfma_f32_16x16x32_bf16(a, b, acc[ei], 0, 0, 0);
    }
  }
  float z[4][4];
  float part[4] = {0.f,0.f,0.f,0.f};
  #pragma unroll
  for (int ei = 0; ei < 4; ++ei){
    int e = e0 + ei*16 + (lane & 15);
    float bb = b2[e];
    #pragma unroll
    for (int r = 0; r < 4; ++r){
      float v = acc[ei][r] + bb;
      z[ei][r] = v;
      part[r] += v * v;
    }
  }
  #pragma unroll
  for (int r = 0; r < 4; ++r){
    float p = part[r];
    p += __shfl_xor(p, 1, 64); p += __shfl_xor(p, 2, 64);
    p += __shfl_xor(p, 4, 64); p += __shfl_xor(p, 8, 64);
    part[r] = p;
  }
  if ((lane & 15) == 0){
    #pragma unroll
    for (int r = 0; r < 4; ++r) ssum[wave][((lane >> 4) << 2) + r] = part[r];
  }
  __syncthreads();
  #pragma unroll
  for (int r = 0; r < 4; ++r){
    int mrow = ((lane >> 4) << 2) + r;
    float tot = ssum[0][mrow] + ssum[1][mrow] + ssum[2][mrow] + ssum[3][mrow];
    float sc = 1.f / fmaxf(sqrtf(tot), 1e-12f);
    #pragma unroll
    for (int ei = 0; ei < 4; ++ei){
      int e = e0 + ei*16 + (lane & 15);
      f[(size_t)(m0 + mrow) * FDIM + e] = f2bf(z[ei][r] * sc);
    }
  }
}

// ---------------------------------------------------------------- logits = fa . fb^T / TEMP
// Also writes LT = logits^T when LT != nullptr: logits(fT,fS) == logits(fS,fT)^T
// exactly, so the second logits dispatch is algebraically redundant. Transpose goes
// through a 17-padded LDS tile so LT rows are written as 64B-coalesced chunks.
__global__ __launch_bounds__(64) void logits_kernel(
    const short* __restrict__ fa, const short* __restrict__ fb,
    float* __restrict__ L, float* __restrict__ LT){
  __shared__ float trl[64 * 17];
  const int lane = threadIdx.x;
  const int m0 = blockIdx.x * 16;
  const int n0 = blockIdx.y * 64;
  f32x4 acc[4] = {};
  for (int kk = 0; kk < FDIM; kk += 32){
    bf16x8 a = ldfrag(fa, FDIM, m0, kk, lane);
    #pragma unroll
    for (int ni = 0; ni < 4; ++ni){
      bf16x8 b = ldfrag(fb, FDIM, n0 + ni*16, kk, lane);
      acc[ni] = __builtin_amdgcn_mfma_f32_16x16x32_bf16(a, b, acc[ni], 0, 0, 0);
    }
  }
  #pragma unroll
  for (int ni = 0; ni < 4; ++ni){
    int colL = ni*16 + (lane & 15);
    #pragma unroll
    for (int r = 0; r < 4; ++r){
      int rowL = ((lane >> 4) << 2) + r;
      float val = acc[ni][r] * TEMP_INV;
      L[(size_t)(m0 + rowL) * M_PAD + (n0 + colL)] = val;
      trl[colL * 17 + rowL] = val;
    }
  }
  if (LT){
    __syncthreads();
    float* dst = LT + (size_t)(n0 + lane) * M_PAD + m0;
    #pragma unroll
    for (int jq = 0; jq < 4; ++jq){
      f32x4 tmp;
      tmp.x = trl[lane*17 + jq*4+0];
      tmp.y = trl[lane*17 + jq*4+1];
      tmp.z = trl[lane*17 + jq*4+2];
      tmp.w = trl[lane*17 + jq*4+3];
      *(f32x4*)(dst + jq*4) = tmp;
    }
  }
}

// ---------------------------------------------------------------- per-row contrastive reduction
__global__ __launch_bounds__(256) void loss_kernel(
    const float* __restrict__ L, const int* __restrict__ labels, float* __restrict__ out){
  __shared__ float row[M_N];
  __shared__ float red[4];
  const int m1 = blockIdx.x;
  const int tid = threadIdx.x;
  const int lab1 = labels[m1 % A_N];
  const float* Lr = L + (size_t)m1 * M_PAD;

  float mx = -3.4e38f;
  for (int j = tid; j < M_N; j += 256){ float v = Lr[j]; row[j] = v; mx = fmaxf(mx, v); }
  #pragma unroll
  for (int s = 1; s < 64; s <<= 1) mx = fmaxf(mx, __shfl_xor(mx, s, 64));
  if ((tid & 63) == 0) red[tid >> 6] = mx;
  __syncthreads();
  mx = fmaxf(fmaxf(red[0], red[1]), fmaxf(red[2], red[3]));
  __syncthreads();

  float negp = 0.f;
  for (int j = tid; j < M_N; j += 256){
    int labj = labels[j % A_N];
    float e = __expf(row[j] - mx);
    negp += (labj != lab1) ? e : 0.f;
  }
  #pragma unroll
  for (int s = 1; s < 64; s <<= 1) negp += __shfl_xor(negp, s, 64);
  if ((tid & 63) == 0) red[tid >> 6] = negp;
  __syncthreads();
  float neg = red[0] + red[1] + red[2] + red[3];
  __syncthreads();

  float ps = 0.f, pc = 0.f;
  for (int j = tid; j < M_N; j += 256){
    int labj = labels[j % A_N];
    if (labj == lab1 && j != m1){
      float l = row[j] - mx;
      ps += l - __logf(__expf(l) + neg);
      pc += 1.f;
    }
  }
  #pragma unroll
  for (int s = 1; s < 64; s <<= 1) ps += __shfl_xor(ps, s, 64);
  #pragma unroll
  for (int s = 1; s < 64; s <<= 1) pc += __shfl_xor(pc, s, 64);
  if ((tid & 63) == 0) red[tid >> 6] = ps;
  __syncthreads();
  ps = red[0] + red[1] + red[2] + red[3];
  __syncthreads();
  if ((tid & 63) == 0) red[tid >> 6] = pc;
  __syncthreads();
  if (tid == 0){
    pc = red[0] + red[1] + red[2] + red[3];
    float mlpp = ps / (pc + 1e-6f);
    atomicAdd(out, -0.5f / (float)M_N * mlpp);
  }
}

// ---------------------------------------------------------------- host launch
extern "C" void kernel_launch(void* const* d_in, const int* in_sizes, int n_in,
                              void* d_out, int out_size, void* d_ws, size_t ws_size,
                              hipStream_t stream){
  const float* xS     = (const float*)d_in[0];
  const float* xT     = (const float*)d_in[1];
  const int*   sb     = (const int*)d_in[2];
  const int*   si     = (const int*)d_in[3];
  const int*   labels = (const int*)d_in[4];
  const float* sW1    = (const float*)d_in[5];
  const float* sGamma = (const float*)d_in[7];
  const float* sBeta  = (const float*)d_in[8];
  const float* sW2    = (const float*)d_in[9];
  const float* sB2    = (const float*)d_in[10];
  const float* tW1    = (const float*)d_in[11];
  const float* tGamma = (const float*)d_in[13];
  const float* tBeta  = (const float*)d_in[14];
  const float* tW2    = (const float*)d_in[15];
  const float* tB2    = (const float*)d_in[16];
  float* out = (float*)d_out;

  char* ws = (char*)d_ws;
  size_t off = 0;
  auto alloc = [&](size_t bytes) -> void* {
    void* p = ws + off;
    off = (off + bytes + 255) & ~(size_t)255;
    return p;
  };
  short* w1bS = (short*)alloc((size_t)CIN * CIN * 2);
  short* w1bT = (short*)alloc((size_t)CIN * CIN * 2);
  short* w2bS = (short*)alloc((size_t)FDIM * CIN * 2);
  short* w2bT = (short*)alloc((size_t)FDIM * CIN * 2);
  float* stats = (float*)alloc(2 * 1024 * 4);
  int* counts = (int*)alloc(NGRP * 4);
  int* lists  = (int*)alloc((size_t)NGRP * LCAP * 4);
  short* xsS = (short*)alloc((size_t)M_N * CIN * 2);
  short* xsT = (short*)alloc((size_t)M_N * CIN * 2);
  short* hrS = (short*)alloc((size_t)M_N * CIN * 2);
  short* hrT = (short*)alloc((size_t)M_N * CIN * 2);
  short* fS  = (short*)alloc((size_t)M_PAD * FDIM * 2);
  short* fT  = (short*)alloc((size_t)M_PAD * FDIM * 2);
  float* L   = (float*)alloc((size_t)M_N * M_PAD * 4);
  float* LT  = (float*)alloc((size_t)M_PAD * M_PAD * 4);
  const bool haveLT = (off <= ws_size);   // fall back to two logits passes if tight

  hipMemsetAsync(d_out, 0, sizeof(float), stream);
  hipMemsetAsync(stats, 0, 2 * 1024 * 4, stream);
  hipMemsetAsync(counts, 0, NGRP * 4, stream);
  // zero padded f rows so logits tiles touching them stay finite
  hipMemsetAsync(fS + (size_t)M_N * FDIM, 0, (size_t)(M_PAD - M_N) * FDIM * 2, stream);
  hipMemsetAsync(fT + (size_t)M_N * FDIM, 0, (size_t)(M_PAD - M_N) * FDIM * 2, stream);

  castw_kernel<<<dim3((CIN*CIN + 255) / 256, 4), 256, 0, stream>>>(
      sW1, w1bS, tW1, w1bT, sW2, w2bS, tW2, w2bT);
  build_lists_kernel<<<dim3((M_N + 63) / 64), 64, 0, stream>>>(sb, si, counts, lists);

  stats_kernel<<<dim3(512, 2), 512, 0, stream>>>(xS, xT, w1bS, w1bT, stats,
                                                 counts, lists, xsS, xsT);
  conv1_kernel<<<dim3(247, 2, 2), 256, 0, stream>>>(xsS, xsT, w1bS, w1bT, stats,
                                                    sGamma, sBeta, tGamma, tBeta, hrS, hrT);
  conv2_kernel<<<dim3(247, 2), 256, 0, stream>>>(hrS, hrT, w2bS, w2bT, sB2, tB2, fS, fT);

  if (haveLT){
    logits_kernel<<<dim3(247, 62), 64, 0, stream>>>(fS, fT, L, LT);
    loss_kernel<<<dim3(M_N), 256, 0, stream>>>(L, labels, out);
    loss_kernel<<<dim3(M_N), 256, 0, stream>>>(LT, labels, out);
  } else {
    logits_kernel<<<dim3(247, 62), 64, 0, stream>>>(fS, fT, L, nullptr);
    loss_kernel<<<dim3(M_N), 256, 0, stream>>>(L, labels, out);
    logits_kernel<<<dim3(247, 62), 64, 0, stream>>>(fT, fS, L, nullptr);
    loss_kernel<<<dim3(M_N), 256, 0, stream>>>(L, labels, out);
  }
}